// Round 2
// baseline (572.692 us; speedup 1.0000x reference)
//
#include <hip/hip_runtime.h>

// LSTM decoder: B=1024, S=256, H=128, O=7, T=512
// gates = h @ (W_ih+W_hh).T + (b_ih+b_hh)  (reference uses h for BOTH matmuls)
// c' = sig(f)*c + sig(i)*tanh(g); h' = sig(o)*tanh(c'); pred = h' @ W_out.T + b_out
//
// Round 2: RB=2 rows/block, 512 blocks x 512 threads -> 2 blocks/CU (4 waves/SIMD)
// so two independent per-step chains overlap. h_lds swizzle fixed to 64B granule
// (conflict-free A-frag reads). wpred moved to LDS to keep VGPR <= 128.

#define RB   2      // batch rows per block
#define HH   128
#define SSEQ 256
#define TT   512
#define OO   7

typedef __attribute__((ext_vector_type(8))) short short8;
typedef __attribute__((ext_vector_type(4))) float f32x4;

__device__ __forceinline__ unsigned short f2bf(float x) {
    union { float f; unsigned u; } v; v.f = x;
    return (unsigned short)((v.u + 0x7FFF + ((v.u >> 16) & 1)) >> 16); // RNE
}

__device__ __forceinline__ float sigmoidf_(float x) {
    return __builtin_amdgcn_rcpf(1.f + __expf(-x));
}
__device__ __forceinline__ float tanhf_(float x) {
    return 1.f - 2.f * __builtin_amdgcn_rcpf(__expf(2.f * x) + 1.f);
}

__global__ __launch_bounds__(512, 4)
void lstm_decoder_kernel(const float* __restrict__ ctx,
                         const float* __restrict__ Wih,
                         const float* __restrict__ Whh,
                         const float* __restrict__ bih,
                         const float* __restrict__ bhh,
                         const float* __restrict__ Wout,
                         const float* __restrict__ bout,
                         float* __restrict__ out) {
    // h state: bf16, double buffered. Swizzle: idx = row*128 + (j ^ ((row&1)*32))
    // -> row parity selects 64B bank half; A-frag ds_read_b128 conflict-free.
    __shared__ __align__(16) unsigned short h_lds[2][RB * HH];
    // W_out bf16 tile (16 rows, cols>=7 zeroed), read per step by wave 0
    __shared__ __align__(16) unsigned short wo_lds[16 * HH];
    // wave-private gate scratch: [wave][g*64 + row*16 + col]
    __shared__ float gsc[8][256];

    const int tid  = threadIdx.x;
    const int lane = tid & 63;
    const int wave = tid >> 6;
    const int rowBase = blockIdx.x * RB;

    const int lo = lane & 15;
    const int hi = lane >> 4;
    const int ej = wave * 16 + lo;    // gate column owned by this lane (0..127)

    // folded biases (i,f,g,o) for this lane's gate column
    const float bi  = bih[ej]          + bhh[ej];
    const float bf_ = bih[HH + ej]     + bhh[HH + ej];
    const float bg  = bih[2 * HH + ej] + bhh[2 * HH + ej];
    const float bo  = bih[3 * HH + ej] + bhh[3 * HH + ej];
    const float bo_pred = (lo < OO) ? bout[lo] : 0.f;

    // W fragments (B-operand) in registers: wave w, gate g -> n = g*128 + w*16 + lo
    // lane holds W[n][k0..k0+7], k0 = kt*32 + hi*8
    short8 wfrag[4][4];
#pragma unroll
    for (int g = 0; g < 4; ++g) {
        const int n = g * HH + wave * 16 + lo;
#pragma unroll
        for (int kt = 0; kt < 4; ++kt) {
            const int k0 = kt * 32 + hi * 8;
            const float* p1 = Wih + (size_t)n * HH + k0;
            const float* p2 = Whh + (size_t)n * HH + k0;
            short8 w;
#pragma unroll
            for (int j = 0; j < 8; ++j) w[j] = (short)f2bf(p1[j] + p2[j]);
            wfrag[g][kt] = w;
        }
    }

    // W_out (bf16, zero-padded to 16 output cols) into LDS
    for (int i = tid; i < 16 * HH; i += 512) {
        const int c = i >> 7, k = i & 127;
        wo_lds[i] = (c < OO) ? f2bf(Wout[(size_t)c * HH + k]) : (unsigned short)0;
    }

    // h0 = context_seq[:, S-1, :]
    if (hi < RB) {
        const float v = ctx[(size_t)(rowBase + hi) * SSEQ * HH + (size_t)(SSEQ - 1) * HH + ej];
        h_lds[0][hi * HH + (ej ^ ((hi & 1) * 32))] = f2bf(v);
    }
    float c_st = 0.f;   // cell state for (row=hi, col=ej); valid for hi < RB
    __syncthreads();

    const int arw = lo & (RB - 1);   // A-tile row, real rows replicated to 16

    for (int it = 0; it <= TT; ++it) {
        const int cur = it & 1;

        // A fragments: lane holds h[arw][k0..k0+7]
        short8 afrag[4];
#pragma unroll
        for (int kt = 0; kt < 4; ++kt) {
            const int k0 = kt * 32 + hi * 8;
            afrag[kt] = *(const short8*)&h_lds[cur][arw * HH + (k0 ^ ((arw & 1) * 32))];
        }

        // pred = h_it @ Wout.T  (h_it is h_new of iteration it-1 -> output step it-1)
        if (wave == 0) {
            f32x4 accp = {0.f, 0.f, 0.f, 0.f};
#pragma unroll
            for (int kt = 0; kt < 4; ++kt) {
                const short8 wp = *(const short8*)&wo_lds[lo * HH + kt * 32 + hi * 8];
                accp = __builtin_amdgcn_mfma_f32_16x16x32_bf16(afrag[kt], wp, accp, 0, 0, 0);
            }
            if (it > 0 && hi == 0 && lo < OO) {
#pragma unroll
                for (int r = 0; r < RB; ++r)
                    out[(size_t)(rowBase + r) * TT * OO + (size_t)(it - 1) * OO + lo] =
                        accp[r] + bo_pred;
            }
        }

        if (it == TT) break;

        // gate MFMAs: 4 gate tiles x 4 K-tiles
        f32x4 acc0 = {0.f, 0.f, 0.f, 0.f};
        f32x4 acc1 = {0.f, 0.f, 0.f, 0.f};
        f32x4 acc2 = {0.f, 0.f, 0.f, 0.f};
        f32x4 acc3 = {0.f, 0.f, 0.f, 0.f};
#pragma unroll
        for (int kt = 0; kt < 4; ++kt) {
            acc0 = __builtin_amdgcn_mfma_f32_16x16x32_bf16(afrag[kt], wfrag[0][kt], acc0, 0, 0, 0);
            acc1 = __builtin_amdgcn_mfma_f32_16x16x32_bf16(afrag[kt], wfrag[1][kt], acc1, 0, 0, 0);
            acc2 = __builtin_amdgcn_mfma_f32_16x16x32_bf16(afrag[kt], wfrag[2][kt], acc2, 0, 0, 0);
            acc3 = __builtin_amdgcn_mfma_f32_16x16x32_bf16(afrag[kt], wfrag[3][kt], acc3, 0, 0, 0);
        }

        // redistribute gates: C/D rows live in lanes 0..15 regs 0..3 ->
        // spread to all 64 lanes via wave-private LDS (same-wave DS in-order).
        if (hi == 0) {
            float* gw = &gsc[wave][lo];
#pragma unroll
            for (int r = 0; r < 4; ++r) {
                gw[0 * 64 + r * 16] = acc0[r];
                gw[1 * 64 + r * 16] = acc1[r];
                gw[2 * 64 + r * 16] = acc2[r];
                gw[3 * 64 + r * 16] = acc3[r];
            }
        }
        const float* gr = &gsc[wave][hi * 16 + lo];
        const float gi = gr[0]   + bi;
        const float gf = gr[64]  + bf_;
        const float gg = gr[128] + bg;
        const float go = gr[192] + bo;

        const float si_ = sigmoidf_(gi);
        const float sf_ = sigmoidf_(gf);
        const float so_ = sigmoidf_(go);
        const float tg  = tanhf_(gg);
        c_st = sf_ * c_st + si_ * tg;
        const float hnew = so_ * tanhf_(c_st);

        if (hi < RB)
            h_lds[cur ^ 1][hi * HH + (ej ^ ((hi & 1) * 32))] = f2bf(hnew);
        __syncthreads();
    }
}

extern "C" void kernel_launch(void* const* d_in, const int* in_sizes, int n_in,
                              void* d_out, int out_size, void* d_ws, size_t ws_size,
                              hipStream_t stream) {
    const float* ctx  = (const float*)d_in[0];
    const float* Wih  = (const float*)d_in[1];
    const float* Whh  = (const float*)d_in[2];
    const float* bih  = (const float*)d_in[3];
    const float* bhh  = (const float*)d_in[4];
    const float* Wout = (const float*)d_in[5];
    const float* bout = (const float*)d_in[6];
    float* out = (float*)d_out;

    lstm_decoder_kernel<<<dim3(1024 / RB), dim3(512), 0, stream>>>(
        ctx, Wih, Whh, bih, bhh, Wout, bout, out);
}

// Round 3
// 546.381 us; speedup vs baseline: 1.0482x; 1.0482x over previous
//
#include <hip/hip_runtime.h>

// LSTM decoder: B=1024, S=256, H=128, O=7, T=512
// gates = h @ (W_ih+W_hh).T + (b_ih+b_hh)  (reference uses h for BOTH matmuls)
// c' = sig(f)*c + sig(i)*tanh(g); h' = sig(o)*tanh(c'); pred = h' @ W_out.T + b_out
//
// Round 3: 512 blocks x 512 thr, RB=2, target 2 blocks/CU pinned via
// amdgpu_waves_per_eu(4,4) (round 2's launch_bounds let the allocator chase
// 8 waves/EU -> 64 VGPR + per-iter spills = 290MB scratch traffic).
// Pred tile on wave 7 from lane-indexed LDS fragments (conflict-free,
// replaces round-2's 16-way-conflict wo_lds reads). Gate scatter vectorized:
// 2x ds_write_b128 + 1x ds_read_b128 per wave.

#define RB   2      // batch rows per block
#define HH   128
#define SSEQ 256
#define TT   512
#define OO   7

typedef __attribute__((ext_vector_type(8))) short short8;
typedef __attribute__((ext_vector_type(4))) float f32x4;

__device__ __forceinline__ unsigned short f2bf(float x) {
    union { float f; unsigned u; } v; v.f = x;
    return (unsigned short)((v.u + 0x7FFF + ((v.u >> 16) & 1)) >> 16); // RNE
}

__device__ __forceinline__ float sigmoidf_(float x) {
    return __builtin_amdgcn_rcpf(1.f + __expf(-x));
}
__device__ __forceinline__ float tanhf_(float x) {
    return 1.f - 2.f * __builtin_amdgcn_rcpf(__expf(2.f * x) + 1.f);
}

__global__ void __launch_bounds__(512)
__attribute__((amdgpu_waves_per_eu(4, 4)))
lstm_decoder_kernel(const float* __restrict__ ctx,
                    const float* __restrict__ Wih,
                    const float* __restrict__ Whh,
                    const float* __restrict__ bih,
                    const float* __restrict__ bhh,
                    const float* __restrict__ Wout,
                    const float* __restrict__ bout,
                    float* __restrict__ out) {
    // h state: bf16, double buffered; row-parity XOR swizzle (64B granule)
    // -> A-frag ds_read_b128 and h-writes conflict-free.
    __shared__ __align__(16) unsigned short h_lds[2][RB * HH];
    // pred B-fragments, lane-indexed: wo_frag[kt][lane][8] (full-BW reads)
    __shared__ __align__(16) unsigned short wo_frag[4][64][8];
    // gate scratch: [wave][lo][row(pad 4)][gate] floats
    __shared__ __align__(16) float gsc[8][16][4][4];

    const int tid  = threadIdx.x;
    const int lane = tid & 63;
    const int wave = tid >> 6;
    const int rowBase = blockIdx.x * RB;

    const int lo = lane & 15;
    const int hi = lane >> 4;
    const int ej = wave * 16 + lo;    // gate column owned by this lane (0..127)

    // folded biases (i,f,g,o) for this lane's gate column
    const float bi  = bih[ej]          + bhh[ej];
    const float bf_ = bih[HH + ej]     + bhh[HH + ej];
    const float bg  = bih[2 * HH + ej] + bhh[2 * HH + ej];
    const float bo  = bih[3 * HH + ej] + bhh[3 * HH + ej];
    const float bo_pred = (lo < OO) ? bout[lo] : 0.f;

    // W fragments (B-operand) in registers: wave w, gate g -> n = g*128 + w*16 + lo
    // lane holds W[n][k0..k0+7], k0 = kt*32 + hi*8
    short8 wfrag[4][4];
#pragma unroll
    for (int g = 0; g < 4; ++g) {
        const int n = g * HH + wave * 16 + lo;
#pragma unroll
        for (int kt = 0; kt < 4; ++kt) {
            const int k0 = kt * 32 + hi * 8;
            const float* p1 = Wih + (size_t)n * HH + k0;
            const float* p2 = Whh + (size_t)n * HH + k0;
            short8 w;
#pragma unroll
            for (int j = 0; j < 8; ++j) w[j] = (short)f2bf(p1[j] + p2[j]);
            wfrag[g][kt] = w;
        }
    }

    // pred B-fragments into LDS (built by wave 0, consumed by wave 7)
    if (tid < 64) {
        const int col = tid & 15;   // W_out row (output col), pad >=7 with 0
        const int kc  = tid >> 4;
#pragma unroll
        for (int kt = 0; kt < 4; ++kt) {
            short8 w;
#pragma unroll
            for (int j = 0; j < 8; ++j)
                w[j] = (col < OO) ? (short)f2bf(Wout[(size_t)col * HH + kt * 32 + kc * 8 + j])
                                  : (short)0;
            *(short8*)&wo_frag[kt][tid][0] = w;
        }
    }

    // h0 = context_seq[:, S-1, :]
    if (hi < RB) {
        const float v = ctx[(size_t)(rowBase + hi) * SSEQ * HH + (size_t)(SSEQ - 1) * HH + ej];
        h_lds[0][hi * HH + (ej ^ (hi * 32))] = f2bf(v);
    }
    float c_st = 0.f;   // cell state for (row=hi, col=ej); valid for hi < RB
    __syncthreads();

    const int arw = lo & (RB - 1);   // A-tile row, real rows replicated to 16

    for (int it = 0; it <= TT; ++it) {
        const int cur = it & 1;

        // A fragments: lane holds h[arw][k0..k0+7]
        short8 afrag[4];
#pragma unroll
        for (int kt = 0; kt < 4; ++kt) {
            const int k0 = kt * 32 + hi * 8;
            afrag[kt] = *(const short8*)&h_lds[cur][arw * HH + (k0 ^ (arw * 32))];
        }

        // pred = h_it @ Wout.T on wave 7 (pred phase first: wp regs die
        // before gate accs are born -> lower peak VGPR pressure)
        if (wave == 7) {
            f32x4 accp = {0.f, 0.f, 0.f, 0.f};
#pragma unroll
            for (int kt = 0; kt < 4; ++kt) {
                const short8 wp = *(const short8*)&wo_frag[kt][lane][0];
                accp = __builtin_amdgcn_mfma_f32_16x16x32_bf16(afrag[kt], wp, accp, 0, 0, 0);
            }
            if (it > 0 && hi == 0 && lo < OO) {
#pragma unroll
                for (int r = 0; r < RB; ++r)
                    out[(size_t)(rowBase + r) * TT * OO + (size_t)(it - 1) * OO + lo] =
                        accp[r] + bo_pred;
            }
        }

        if (it == TT) break;

        // gate MFMAs: 4 gate tiles x 4 K-tiles
        f32x4 acc0 = {0.f, 0.f, 0.f, 0.f};
        f32x4 acc1 = {0.f, 0.f, 0.f, 0.f};
        f32x4 acc2 = {0.f, 0.f, 0.f, 0.f};
        f32x4 acc3 = {0.f, 0.f, 0.f, 0.f};
#pragma unroll
        for (int kt = 0; kt < 4; ++kt) {
            acc0 = __builtin_amdgcn_mfma_f32_16x16x32_bf16(afrag[kt], wfrag[0][kt], acc0, 0, 0, 0);
            acc1 = __builtin_amdgcn_mfma_f32_16x16x32_bf16(afrag[kt], wfrag[1][kt], acc1, 0, 0, 0);
            acc2 = __builtin_amdgcn_mfma_f32_16x16x32_bf16(afrag[kt], wfrag[2][kt], acc2, 0, 0, 0);
            acc3 = __builtin_amdgcn_mfma_f32_16x16x32_bf16(afrag[kt], wfrag[3][kt], acc3, 0, 0, 0);
        }

        // redistribute gates: rows 0..RB-1 live in lanes hi==0, regs 0..RB-1.
        // Vector scatter: [wave][lo][r][g] layout -> 2x ds_write_b128, then
        // each lane (hi<RB) gathers its 4 gates with 1x ds_read_b128.
        // Same-wave DS ops are in-order; gsc is wave-private -> no barrier.
        if (hi == 0) {
            const f32x4 r0 = {acc0[0], acc1[0], acc2[0], acc3[0]};
            const f32x4 r1 = {acc0[1], acc1[1], acc2[1], acc3[1]};
            *(f32x4*)&gsc[wave][lo][0][0] = r0;
            *(f32x4*)&gsc[wave][lo][1][0] = r1;
        }
        const f32x4 g4 = *(const f32x4*)&gsc[wave][lo][hi][0];  // hi>=RB reads padding

        const float gi = g4[0] + bi;
        const float gf = g4[1] + bf_;
        const float gg = g4[2] + bg;
        const float go = g4[3] + bo;

        const float si_ = sigmoidf_(gi);
        const float sf_ = sigmoidf_(gf);
        const float so_ = sigmoidf_(go);
        const float tg  = tanhf_(gg);
        c_st = sf_ * c_st + si_ * tg;
        const float hnew = so_ * tanhf_(c_st);

        if (hi < RB)
            h_lds[cur ^ 1][hi * HH + (ej ^ (hi * 32))] = f2bf(hnew);
        __syncthreads();
    }
}

extern "C" void kernel_launch(void* const* d_in, const int* in_sizes, int n_in,
                              void* d_out, int out_size, void* d_ws, size_t ws_size,
                              hipStream_t stream) {
    const float* ctx  = (const float*)d_in[0];
    const float* Wih  = (const float*)d_in[1];
    const float* Whh  = (const float*)d_in[2];
    const float* bih  = (const float*)d_in[3];
    const float* bhh  = (const float*)d_in[4];
    const float* Wout = (const float*)d_in[5];
    const float* bout = (const float*)d_in[6];
    float* out = (float*)d_out;

    lstm_decoder_kernel<<<dim3(1024 / RB), dim3(512), 0, stream>>>(
        ctx, Wih, Whh, bih, bhh, Wout, bout, out);
}

// Round 4
// 473.005 us; speedup vs baseline: 1.2108x; 1.1551x over previous
//
#include <hip/hip_runtime.h>

// LSTM decoder: B=1024, S=256, H=128, O=7, T=512
// gates = h @ (W_ih+W_hh).T + (b_ih+b_hh); c'=sig(f)c+sig(i)tanh(g);
// h'=sig(o)tanh(c'); pred = h' @ W_out.T + b_out
//
// Round 4: 256 blocks x 1024 thr (16 waves), RB=4, 1 block/CU, 4 waves/SIMD.
// K=128 split across wave pairs (kh=wave&1): per wave 4 gate tiles x 2 K-tiles
// -> wfrag 32 VGPR (round 2/3's 64-VGPR wfrag sat on the 128-reg cliff and the
// arch/AGPR split spilled). Partials summed via padded LDS; 2 barriers/step.
// Pred tile split across waves 14/15, stored by wave 15 (idle in phase B).

#define HH   128
#define SSEQ 256
#define TT   512
#define OO   7
#define RB   4

typedef __attribute__((ext_vector_type(8))) short short8;
typedef __attribute__((ext_vector_type(4))) float f32x4;

__device__ __forceinline__ unsigned short f2bf(float x) {
    union { float f; unsigned u; } v; v.f = x;
    return (unsigned short)((v.u + 0x7FFF + ((v.u >> 16) & 1)) >> 16); // RNE
}
__device__ __forceinline__ float sigmoidf_(float x) {
    return __builtin_amdgcn_rcpf(1.f + __expf(-x));
}
__device__ __forceinline__ float tanhf_(float x) {
    return 1.f - 2.f * __builtin_amdgcn_rcpf(__expf(2.f * x) + 1.f);
}

__global__ void __launch_bounds__(1024, 4)
lstm_decoder_kernel(const float* __restrict__ ctx,
                    const float* __restrict__ Wih,
                    const float* __restrict__ Whh,
                    const float* __restrict__ bih,
                    const float* __restrict__ bhh,
                    const float* __restrict__ Wout,
                    const float* __restrict__ bout,
                    float* __restrict__ out) {
    // h: bf16, double-buffered, row-parity XOR swizzle (64B granule) -> A reads clean
    __shared__ __align__(16) unsigned short h_lds[2][RB * HH];
    // gate partials: [cb][lo][r*8 + kh*4 + g], padded 32->44 floats (2-phase writes)
    __shared__ __align__(16) float gsc[8][16][44];
    // pred partials: [kh][lo][r]
    __shared__ __align__(16) float gscp[2][16][4];

    const int tid  = threadIdx.x;
    const int lane = tid & 63;
    const int wave = tid >> 6;
    const int rowBase = blockIdx.x * RB;

    const int lo = lane & 15;
    const int hi = lane >> 4;
    const int kh = wave & 1;      // K half (kt pair 2kh, 2kh+1)
    const int cb = wave >> 1;     // column block (j = 16*cb .. 16*cb+15)
    const int arw = lo & 3;       // A-tile real row (rows replicated to 16)

    // elementwise role: waves 0..7, thread -> (erow, ej)
    const bool ew  = wave < 8;
    const int erow = wave >> 1;
    const int ej   = (wave & 1) * 64 + lane;

    float bi = 0.f, bf_ = 0.f, bg = 0.f, bo = 0.f;
    if (ew) {
        bi  = bih[ej]          + bhh[ej];
        bf_ = bih[HH + ej]     + bhh[HH + ej];
        bg  = bih[2 * HH + ej] + bhh[2 * HH + ej];
        bo  = bih[3 * HH + ej] + bhh[3 * HH + ej];
    }

    // W fragments: gate g tile at this wave's (cb, kh): n = g*128 + cb*16 + lo,
    // lane holds W[n][k0..k0+7], k0 = (2kh+t)*32 + hi*8
    short8 wfrag[4][2];
#pragma unroll
    for (int g = 0; g < 4; ++g) {
        const int n = g * HH + cb * 16 + lo;
#pragma unroll
        for (int t = 0; t < 2; ++t) {
            const int k0 = (2 * kh + t) * 32 + hi * 8;
            const float* p1 = Wih + (size_t)n * HH + k0;
            const float* p2 = Whh + (size_t)n * HH + k0;
            short8 w;
#pragma unroll
            for (int j = 0; j < 8; ++j) w[j] = (short)f2bf(p1[j] + p2[j]);
            wfrag[g][t] = w;
        }
    }

    // pred B-fragments on waves 14 (kh=0) / 15 (kh=1); cols >= OO zero-padded
    short8 wpred[2];
    float bo_pred = 0.f;
    if (wave >= 14) {
#pragma unroll
        for (int t = 0; t < 2; ++t) {
            const int k0 = (2 * kh + t) * 32 + hi * 8;
            short8 w;
#pragma unroll
            for (int j = 0; j < 8; ++j)
                w[j] = (lo < OO) ? (short)f2bf(Wout[(size_t)lo * HH + k0 + j]) : (short)0;
            wpred[t] = w;
        }
        if (wave == 15 && lo < OO) bo_pred = bout[lo];
    }

    // h0 = context_seq[:, S-1, :]
    if (ew) {
        const float v = ctx[(size_t)(rowBase + erow) * SSEQ * HH + (size_t)(SSEQ - 1) * HH + ej];
        h_lds[0][erow * HH + (ej ^ ((erow & 1) * 32))] = f2bf(v);
    }
    float c_st = 0.f;
    __syncthreads();

    for (int it = 0; it < TT; ++it) {
        const int cur = it & 1;

        // ---- phase A: MFMA partials ----
        const int k00 = 2 * kh * 32 + hi * 8;
        const short8 a0 = *(const short8*)&h_lds[cur][arw * HH + (k00 ^ ((arw & 1) * 32))];
        const short8 a1 = *(const short8*)&h_lds[cur][arw * HH + ((k00 + 32) ^ ((arw & 1) * 32))];

        f32x4 acc0 = {0.f, 0.f, 0.f, 0.f};
        f32x4 acc1 = {0.f, 0.f, 0.f, 0.f};
        f32x4 acc2 = {0.f, 0.f, 0.f, 0.f};
        f32x4 acc3 = {0.f, 0.f, 0.f, 0.f};
        acc0 = __builtin_amdgcn_mfma_f32_16x16x32_bf16(a0, wfrag[0][0], acc0, 0, 0, 0);
        acc1 = __builtin_amdgcn_mfma_f32_16x16x32_bf16(a0, wfrag[1][0], acc1, 0, 0, 0);
        acc2 = __builtin_amdgcn_mfma_f32_16x16x32_bf16(a0, wfrag[2][0], acc2, 0, 0, 0);
        acc3 = __builtin_amdgcn_mfma_f32_16x16x32_bf16(a0, wfrag[3][0], acc3, 0, 0, 0);
        acc0 = __builtin_amdgcn_mfma_f32_16x16x32_bf16(a1, wfrag[0][1], acc0, 0, 0, 0);
        acc1 = __builtin_amdgcn_mfma_f32_16x16x32_bf16(a1, wfrag[1][1], acc1, 0, 0, 0);
        acc2 = __builtin_amdgcn_mfma_f32_16x16x32_bf16(a1, wfrag[2][1], acc2, 0, 0, 0);
        acc3 = __builtin_amdgcn_mfma_f32_16x16x32_bf16(a1, wfrag[3][1], acc3, 0, 0, 0);

        // scatter partials (C/D: col=lane&15, row=4*hi+reg; real row = reg, dup over hi)
        if (hi == 0) {
#pragma unroll
            for (int r = 0; r < 4; ++r) {
                const f32x4 v = {acc0[r], acc1[r], acc2[r], acc3[r]};
                *(f32x4*)&gsc[cb][lo][r * 8 + kh * 4] = v;
            }
        }
        if (wave >= 14) {
            f32x4 accp = {0.f, 0.f, 0.f, 0.f};
            accp = __builtin_amdgcn_mfma_f32_16x16x32_bf16(a0, wpred[0], accp, 0, 0, 0);
            accp = __builtin_amdgcn_mfma_f32_16x16x32_bf16(a1, wpred[1], accp, 0, 0, 0);
            if (hi == 0) *(f32x4*)&gscp[kh][lo][0] = accp;
        }
        __syncthreads();   // bar1: gate partials visible

        // ---- phase B: elementwise on waves 0..7 ----
        if (ew) {
            const float* rec = &gsc[ej >> 4][ej & 15][erow * 8];
            const f32x4 v0 = *(const f32x4*)&rec[0];
            const f32x4 v1 = *(const f32x4*)&rec[4];
            const float gi = v0[0] + v1[0] + bi;
            const float gf = v0[1] + v1[1] + bf_;
            const float gg = v0[2] + v1[2] + bg;
            const float go = v0[3] + v1[3] + bo;

            const float si_ = sigmoidf_(gi);
            const float sf_ = sigmoidf_(gf);
            const float so_ = sigmoidf_(go);
            const float tg  = tanhf_(gg);
            c_st = sf_ * c_st + si_ * tg;
            const float hnew = so_ * tanhf_(c_st);
            h_lds[cur ^ 1][erow * HH + (ej ^ ((erow & 1) * 32))] = f2bf(hnew);
        }
        // pred of h_it -> out step it-1 (stored by wave 15, idle in phase B)
        if (wave == 15 && it > 0 && lo < OO) {
            const float p = gscp[0][lo][hi] + gscp[1][lo][hi] + bo_pred;
            out[(size_t)(rowBase + hi) * TT * OO + (size_t)(it - 1) * OO + lo] = p;
        }
        __syncthreads();   // bar2: h_lds[cur^1] complete, gsc consumed
    }

    // epilogue: pred of h_TT -> out step TT-1
    if (wave >= 14) {
        const int k00 = 2 * kh * 32 + hi * 8;
        const short8 a0 = *(const short8*)&h_lds[TT & 1][arw * HH + (k00 ^ ((arw & 1) * 32))];
        const short8 a1 = *(const short8*)&h_lds[TT & 1][arw * HH + ((k00 + 32) ^ ((arw & 1) * 32))];
        f32x4 accp = {0.f, 0.f, 0.f, 0.f};
        accp = __builtin_amdgcn_mfma_f32_16x16x32_bf16(a0, wpred[0], accp, 0, 0, 0);
        accp = __builtin_amdgcn_mfma_f32_16x16x32_bf16(a1, wpred[1], accp, 0, 0, 0);
        if (hi == 0) *(f32x4*)&gscp[kh][lo][0] = accp;
    }
    __syncthreads();
    if (wave == 15 && lo < OO) {
        const float p = gscp[0][lo][hi] + gscp[1][lo][hi] + bo_pred;
        out[(size_t)(rowBase + hi) * TT * OO + (size_t)(TT - 1) * OO + lo] = p;
    }
}

extern "C" void kernel_launch(void* const* d_in, const int* in_sizes, int n_in,
                              void* d_out, int out_size, void* d_ws, size_t ws_size,
                              hipStream_t stream) {
    const float* ctx  = (const float*)d_in[0];
    const float* Wih  = (const float*)d_in[1];
    const float* Whh  = (const float*)d_in[2];
    const float* bih  = (const float*)d_in[3];
    const float* bhh  = (const float*)d_in[4];
    const float* Wout = (const float*)d_in[5];
    const float* bout = (const float*)d_in[6];
    float* out = (float*)d_out;

    lstm_decoder_kernel<<<dim3(1024 / RB), dim3(1024), 0, stream>>>(
        ctx, Wih, Whh, bih, bhh, Wout, bout, out);
}

// Round 5
// 344.408 us; speedup vs baseline: 1.6628x; 1.3734x over previous
//
#include <hip/hip_runtime.h>

// LSTM decoder: B=1024, S=256, H=128, O=7, T=512
// gates = h @ (W_ih+W_hh).T + (b_ih+b_hh); c'=sig(f)c+sig(i)tanh(g);
// h'=sig(o)tanh(c'); pred = h' @ W_out.T + b_out
//
// Round 5: back to round-1 skeleton (256 blocks x 512 thr, 8 waves, RB=4,
// 1 barrier/step) but ZERO gate LDS traffic: since A rows are replicated
// (arw=lo&3), MFMA C-layout row=4*hi+reg means every hi group's regs 0..3
// hold the gates for real rows 0..3 -> select reg r=hi via 3 cndmasks and
// do the elementwise update in-register. Each lane writes exactly one bf16
// h_new to LDS. h row stride padded to 136 shorts (4-bank skew): A-frag
// b128 reads and b16 writes both 2-way max (free).

#define HH   128
#define SSEQ 256
#define TT   512
#define OO   7
#define RB   4
#define HSTR 136   // h_lds row stride in shorts (272B = 4-bank skew)

typedef __attribute__((ext_vector_type(8))) short short8;
typedef __attribute__((ext_vector_type(4))) float f32x4;

__device__ __forceinline__ unsigned short f2bf(float x) {
    union { float f; unsigned u; } v; v.f = x;
    return (unsigned short)((v.u + 0x7FFF + ((v.u >> 16) & 1)) >> 16); // RNE
}
__device__ __forceinline__ float sigmoidf_(float x) {
    return __builtin_amdgcn_rcpf(1.f + __expf(-x));
}
__device__ __forceinline__ float tanhf_(float x) {
    return 1.f - 2.f * __builtin_amdgcn_rcpf(__expf(2.f * x) + 1.f);
}

__global__ void __launch_bounds__(512, 2)
lstm_decoder_kernel(const float* __restrict__ ctx,
                    const float* __restrict__ Wih,
                    const float* __restrict__ Whh,
                    const float* __restrict__ bih,
                    const float* __restrict__ bhh,
                    const float* __restrict__ Wout,
                    const float* __restrict__ bout,
                    float* __restrict__ out) {
    __shared__ __align__(16) unsigned short h_lds[2][RB * HSTR];

    const int tid  = threadIdx.x;
    const int lane = tid & 63;
    const int wave = tid >> 6;
    const int rowBase = blockIdx.x * RB;

    const int lo  = lane & 15;
    const int hi  = lane >> 4;       // 0..3: this lane's batch row AND k-slice
    const int col = wave * 16 + lo;  // this lane's gate/h column (0..127)
    const int arw = lo & 3;          // A-tile real row (rows replicated to 16)

    // folded biases for this lane's column
    const float bi  = bih[col]          + bhh[col];
    const float bf_ = bih[HH + col]     + bhh[HH + col];
    const float bg  = bih[2 * HH + col] + bhh[2 * HH + col];
    const float bo  = bih[3 * HH + col] + bhh[3 * HH + col];
    const float bo_pred = (lo < OO) ? bout[lo] : 0.f;

    // W fragments (B-operand): wave w, gate g -> n = g*128 + w*16 + lo,
    // lane holds W[n][k0..k0+7], k0 = kt*32 + hi*8
    short8 wfrag[4][4];
#pragma unroll
    for (int g = 0; g < 4; ++g) {
        const int n = g * HH + wave * 16 + lo;
#pragma unroll
        for (int kt = 0; kt < 4; ++kt) {
            const int k0 = kt * 32 + hi * 8;
            const float* p1 = Wih + (size_t)n * HH + k0;
            const float* p2 = Whh + (size_t)n * HH + k0;
            short8 w;
#pragma unroll
            for (int j = 0; j < 8; ++j) w[j] = (short)f2bf(p1[j] + p2[j]);
            wfrag[g][kt] = w;
        }
    }

    // pred B-fragments on wave 0 (W_out rows = output cols, zero-padded to 16)
    short8 wpred[4];
    if (wave == 0) {
#pragma unroll
        for (int kt = 0; kt < 4; ++kt) {
            const int k0 = kt * 32 + hi * 8;
            short8 w;
#pragma unroll
            for (int j = 0; j < 8; ++j)
                w[j] = (lo < OO) ? (short)f2bf(Wout[(size_t)lo * HH + k0 + j]) : (short)0;
            wpred[kt] = w;
        }
    }

    // h0 = context_seq[:, S-1, :]: lane (hi, col) owns (row hi, col)
    {
        const float v = ctx[(size_t)(rowBase + hi) * SSEQ * HH + (size_t)(SSEQ - 1) * HH + col];
        h_lds[0][hi * HSTR + col] = f2bf(v);
    }
    float c_st = 0.f;   // cell state for (row hi, col)
    __syncthreads();

    for (int it = 0; it <= TT; ++it) {
        const int cur = it & 1;

        // A fragments: lane holds h[arw][k0..k0+7], k0 = kt*32 + hi*8
        const int abase = arw * HSTR + hi * 8;
        short8 afrag[4];
#pragma unroll
        for (int kt = 0; kt < 4; ++kt)
            afrag[kt] = *(const short8*)&h_lds[cur][abase + kt * 32];

        // pred = h_it @ Wout.T on wave 0 (h_it -> output step it-1)
        if (wave == 0) {
            f32x4 accp = {0.f, 0.f, 0.f, 0.f};
#pragma unroll
            for (int kt = 0; kt < 4; ++kt)
                accp = __builtin_amdgcn_mfma_f32_16x16x32_bf16(afrag[kt], wpred[kt], accp, 0, 0, 0);
            if (it > 0 && hi == 0 && lo < OO) {
#pragma unroll
                for (int r = 0; r < RB; ++r)
                    out[(size_t)(rowBase + r) * TT * OO + (size_t)(it - 1) * OO + lo] =
                        accp[r] + bo_pred;
            }
        }

        if (it == TT) break;

        // gate MFMAs: 4 gate tiles x 4 K-tiles
        f32x4 acc0 = {0.f, 0.f, 0.f, 0.f};
        f32x4 acc1 = {0.f, 0.f, 0.f, 0.f};
        f32x4 acc2 = {0.f, 0.f, 0.f, 0.f};
        f32x4 acc3 = {0.f, 0.f, 0.f, 0.f};
#pragma unroll
        for (int kt = 0; kt < 4; ++kt) {
            acc0 = __builtin_amdgcn_mfma_f32_16x16x32_bf16(afrag[kt], wfrag[0][kt], acc0, 0, 0, 0);
            acc1 = __builtin_amdgcn_mfma_f32_16x16x32_bf16(afrag[kt], wfrag[1][kt], acc1, 0, 0, 0);
            acc2 = __builtin_amdgcn_mfma_f32_16x16x32_bf16(afrag[kt], wfrag[2][kt], acc2, 0, 0, 0);
            acc3 = __builtin_amdgcn_mfma_f32_16x16x32_bf16(afrag[kt], wfrag[3][kt], acc3, 0, 0, 0);
        }

        // C row = 4*hi + reg; A row m holds real row m&3 -> reg r at ANY hi is
        // the gate for real row r. Select reg r = hi in-register (no LDS).
        const bool m1 = (hi == 1), m2 = (hi == 2), m3 = (hi == 3);
        const float gi = m3 ? acc0[3] : m2 ? acc0[2] : m1 ? acc0[1] : acc0[0];
        const float gf = m3 ? acc1[3] : m2 ? acc1[2] : m1 ? acc1[1] : acc1[0];
        const float gg = m3 ? acc2[3] : m2 ? acc2[2] : m1 ? acc2[1] : acc2[0];
        const float go = m3 ? acc3[3] : m2 ? acc3[2] : m1 ? acc3[1] : acc3[0];

        const float si_ = sigmoidf_(gi + bi);
        const float sf_ = sigmoidf_(gf + bf_);
        const float so_ = sigmoidf_(go + bo);
        const float tg  = tanhf_(gg + bg);
        c_st = sf_ * c_st + si_ * tg;
        const float hnew = so_ * tanhf_(c_st);

        h_lds[cur ^ 1][hi * HSTR + col] = f2bf(hnew);
        __syncthreads();
    }
}

extern "C" void kernel_launch(void* const* d_in, const int* in_sizes, int n_in,
                              void* d_out, int out_size, void* d_ws, size_t ws_size,
                              hipStream_t stream) {
    const float* ctx  = (const float*)d_in[0];
    const float* Wih  = (const float*)d_in[1];
    const float* Whh  = (const float*)d_in[2];
    const float* bih  = (const float*)d_in[3];
    const float* bhh  = (const float*)d_in[4];
    const float* Wout = (const float*)d_in[5];
    const float* bout = (const float*)d_in[6];
    float* out = (float*)d_out;

    lstm_decoder_kernel<<<dim3(1024 / RB), dim3(512), 0, stream>>>(
        ctx, Wih, Whh, bih, bhh, Wout, bout, out);
}